// Round 1
// 675.783 us; speedup vs baseline: 1.1748x; 1.1748x over previous
//
#include <hip/hip_runtime.h>

#define ZD 256    // Z_NH
#define NE 1000   // NUM_ENTRY
#define NP 1024   // padded entries

typedef __attribute__((ext_vector_type(8))) short short8;
typedef __attribute__((ext_vector_type(4))) float f32x4;

static __device__ __forceinline__ unsigned short f2bf(float x) {
    unsigned u = __float_as_uint(x);
    u = (u + 0x7FFFu + ((u >> 16) & 1u)) >> 16;
    return (unsigned short)u;
}

// exact reference-chain distance: d = fl(fl(hn+en) - 2*fmaf-chain(h,e))
// Chain order is IDENTICAL to the validated scalar version (k ascending,
// single accumulator); only the loads are widened to float4 so the ~500-cycle
// L1/L2 latency is paid per 16B instead of per 4B and batches 8x deeper.
__device__ __attribute__((noinline)) float exact_d(const float* __restrict__ hr,
                                                   const float* __restrict__ er,
                                                   float hn, float ene) {
    float dot = 0.f;
    #pragma unroll 8
    for (int k = 0; k < ZD; k += 4) {
        float4 hv = *(const float4*)(hr + k);
        float4 ev = *(const float4*)(er + k);
        dot = fmaf(hv.x, ev.x, dot);
        dot = fmaf(hv.y, ev.y, dot);
        dot = fmaf(hv.z, ev.z, dot);
        dot = fmaf(hv.w, ev.w, dot);
    }
    return __fsub_rn(__fadd_rn(hn, ene), __fmul_rn(2.0f, dot));
}

// ---------------------------------------------------------------------------
// prep_e: eb (bf16, pre-XOR-swizzled within each 512B row) + en exact pairwise
// ---------------------------------------------------------------------------
__global__ __launch_bounds__(64) void prep_e(const float* __restrict__ emb,
                                             unsigned char* __restrict__ ebB,
                                             float* __restrict__ en) {
    int e = blockIdx.x * 64 + threadIdx.x;
    if (e >= NP) return;
    unsigned base = (unsigned)e * 512u;
    unsigned x = ((unsigned)e & 7u) << 4;
    if (e < NE) {
        const float* row = emb + (size_t)e * ZD;
        for (int k = 0; k < ZD; k += 2) {  // 2k%4==0, pair stays in same dword
            unsigned off = (base + 2u * k) ^ x;
            *(unsigned short*)(ebB + off)     = f2bf(row[k]);
            *(unsigned short*)(ebB + off + 2) = f2bf(row[k + 1]);
        }
        float r[8];
        #pragma unroll
        for (int j = 0; j < 8; ++j) { float v = row[j]; r[j] = __fmul_rn(v, v); }
        for (int i = 8; i < 128; i += 8)
            #pragma unroll
            for (int j = 0; j < 8; ++j) { float v = row[i + j]; r[j] = __fadd_rn(r[j], __fmul_rn(v, v)); }
        float s1 = __fadd_rn(__fadd_rn(__fadd_rn(r[0], r[1]), __fadd_rn(r[2], r[3])),
                             __fadd_rn(__fadd_rn(r[4], r[5]), __fadd_rn(r[6], r[7])));
        #pragma unroll
        for (int j = 0; j < 8; ++j) { float v = row[128 + j]; r[j] = __fmul_rn(v, v); }
        for (int i = 136; i < 256; i += 8)
            #pragma unroll
            for (int j = 0; j < 8; ++j) { float v = row[i + j]; r[j] = __fadd_rn(r[j], __fmul_rn(v, v)); }
        float s2 = __fadd_rn(__fadd_rn(__fadd_rn(r[0], r[1]), __fadd_rn(r[2], r[3])),
                             __fadd_rn(__fadd_rn(r[4], r[5]), __fadd_rn(r[6], r[7])));
        en[e] = __fadd_rn(s1, s2);
    } else {
        for (int k = 0; k < 128; ++k) *(unsigned*)(ebB + base + 4u * k) = 0u;
        en[e] = __builtin_inff();
    }
}

// ---------------------------------------------------------------------------
// prep_h: hb (bf16 rows, stored in out_q region, row stride 512 ushorts) and
// hn (exact numpy-pairwise, stored in out_i region as float bits)
// ---------------------------------------------------------------------------
__global__ __launch_bounds__(256) void prep_h(const float* __restrict__ h,
                                              unsigned short* __restrict__ hb,
                                              float* __restrict__ hn) {
    __shared__ float L[64][257];
    const int t = threadIdx.x;
    const long row0 = (long)blockIdx.x * 64;
    const int kq = (t & 63) * 4;
    const int rq = t >> 6;
    #pragma unroll
    for (int p = 0; p < 16; ++p) {
        int row = p * 4 + rq;
        float4 v = *(const float4*)(h + (row0 + row) * ZD + kq);
        L[row][kq] = v.x; L[row][kq + 1] = v.y; L[row][kq + 2] = v.z; L[row][kq + 3] = v.w;
    }
    __syncthreads();
    #pragma unroll
    for (int p = 0; p < 16; ++p) {
        int row = p * 4 + rq;
        ushort4 o;
        o.x = f2bf(L[row][kq]);     o.y = f2bf(L[row][kq + 1]);
        o.z = f2bf(L[row][kq + 2]); o.w = f2bf(L[row][kq + 3]);
        *(ushort4*)(hb + (row0 + row) * 512 + kq) = o;
    }
    if (t < 64) {
        float r[8];
        #pragma unroll
        for (int j = 0; j < 8; ++j) { float v = L[t][j]; r[j] = __fmul_rn(v, v); }
        for (int i = 8; i < 128; i += 8)
            #pragma unroll
            for (int j = 0; j < 8; ++j) { float v = L[t][i + j]; r[j] = __fadd_rn(r[j], __fmul_rn(v, v)); }
        float s1 = __fadd_rn(__fadd_rn(__fadd_rn(r[0], r[1]), __fadd_rn(r[2], r[3])),
                             __fadd_rn(__fadd_rn(r[4], r[5]), __fadd_rn(r[6], r[7])));
        #pragma unroll
        for (int j = 0; j < 8; ++j) { float v = L[t][128 + j]; r[j] = __fmul_rn(v, v); }
        for (int i = 136; i < 256; i += 8)
            #pragma unroll
            for (int j = 0; j < 8; ++j) { float v = L[t][i + j]; r[j] = __fadd_rn(r[j], __fmul_rn(v, v)); }
        float s2 = __fadd_rn(__fadd_rn(__fadd_rn(r[0], r[1]), __fadd_rn(r[2], r[3])),
                             __fadd_rn(__fadd_rn(r[4], r[5]), __fadd_rn(r[6], r[7])));
        hn[row0 + t] = __fadd_rn(s1, s2);
    }
}

// ---------------------------------------------------------------------------
// main: 16 waves × 16 rows = 256 rows/block. MFMA 16x16x32 bf16 approx
// distances (two 4-deep independent accumulator chains), per-lane top-4,
// exact fmaf-chain re-verification of candidates with float4 loads.
// ---------------------------------------------------------------------------
__global__ __launch_bounds__(1024, 4) void vq_main(const float* __restrict__ h,
                                                   const float* __restrict__ emb,
                                                   const unsigned char* __restrict__ ebB,
                                                   const float* __restrict__ en,
                                                   float* out, int M) {
    extern __shared__ char lds[];
    char* BsB = lds;                          // 131072 B swizzled bf16 chunk
    float* en_s = (float*)(lds + 131072);     // 256 floats

    const int t  = threadIdx.x;
    const int lane = t & 63;
    const int wv = t >> 6;                    // 0..15
    const int g  = lane >> 4;                 // 0..3
    const int lg = lane & 15;
    const long rbase = (long)blockIdx.x * 256 + wv * 16;

    const unsigned short* hb = (const unsigned short*)out;    // bf16 h rows
    const float* hnp = out + (size_t)M * ZD;                  // hn values

    // ---- A fragments: row = rbase+lg, k = kt*32 + g*8 .. +8 (consistent f) ----
    short8 afrag[8];
    {
        const unsigned short* hr = hb + (rbase + lg) * 512;
        #pragma unroll
        for (int kt = 0; kt < 8; ++kt)
            afrag[kt] = *(const short8*)(hr + kt * 32 + g * 8);
    }
    float hnr[4], taur[4];
    #pragma unroll
    for (int i = 0; i < 4; ++i) {
        hnr[i] = hnp[rbase + g * 4 + i];
        taur[i] = 1.0e-5f * sqrtf(256.0f * hnr[i]) + 1.0e-3f;
    }

    const float INF = __builtin_inff();
    float bv0[4], bv1[4], bv2[4], bv3[4];
    int   bi0[4], bi1[4], bi2[4], bi3[4];
    #pragma unroll
    for (int i = 0; i < 4; ++i) {
        bv0[i] = INF; bv1[i] = INF; bv2[i] = INF; bv3[i] = INF;
        bi0[i] = 0;   bi1[i] = 0;   bi2[i] = 0;   bi3[i] = 0;
    }

    for (int c = 0; c < 4; ++c) {
        { // stage pre-swizzled chunk linearly (coalesced, conflict-free)
            const uint4* src = (const uint4*)(ebB + (size_t)c * 131072);
            uint4* dst = (uint4*)BsB;
            #pragma unroll
            for (int p = 0; p < 8; ++p) dst[p * 1024 + t] = src[p * 1024 + t];
        }
        if (t < 64) {
            float4 v = *(const float4*)(en + c * 256 + t * 4);
            *(float4*)(en_s + t * 4) = v;
        }
        __syncthreads();

        for (int nt = 0; nt < 16; ++nt) {
            // two independent 4-deep MFMA chains (approx only; tau covers the
            // summation-order delta, 2*eps ~ 1.5e-4 << tau ~ 3.6e-3)
            f32x4 acc0 = {0.f, 0.f, 0.f, 0.f};
            f32x4 acc1 = {0.f, 0.f, 0.f, 0.f};
            const int nb = nt * 16 + lg;                       // entry in chunk
            const unsigned x = ((unsigned)lg & 7u) << 4;
            const unsigned rowb = (unsigned)nb * 512u;
            #pragma unroll
            for (int kt = 0; kt < 4; ++kt) {
                short8 b0 = *(const short8*)(BsB + ((rowb + (unsigned)kt * 64u + g * 16u) ^ x));
                short8 b1 = *(const short8*)(BsB + ((rowb + (unsigned)(kt + 4) * 64u + g * 16u) ^ x));
                acc0 = __builtin_amdgcn_mfma_f32_16x16x32_bf16(afrag[kt],     b0, acc0, 0, 0, 0);
                acc1 = __builtin_amdgcn_mfma_f32_16x16x32_bf16(afrag[kt + 4], b1, acc1, 0, 0, 0);
            }
            const int eIdx = c * 256 + nb;
            const float ene = en_s[nb];
            #pragma unroll
            for (int i = 0; i < 4; ++i) {
                float dot = __fadd_rn(acc0[i], acc1[i]);
                float d = __fsub_rn(__fadd_rn(hnr[i], ene), __fmul_rn(2.0f, dot));
                if (__any(d < bv3[i])) {
                    bool l3 = d < bv3[i], l2 = d < bv2[i], l1 = d < bv1[i], l0 = d < bv0[i];
                    bv3[i] = l3 ? (l2 ? bv2[i] : d) : bv3[i];
                    bi3[i] = l3 ? (l2 ? bi2[i] : eIdx) : bi3[i];
                    bv2[i] = l2 ? (l1 ? bv1[i] : d) : bv2[i];
                    bi2[i] = l2 ? (l1 ? bi1[i] : eIdx) : bi2[i];
                    bv1[i] = l1 ? (l0 ? bv0[i] : d) : bv1[i];
                    bi1[i] = l1 ? (l0 ? bi0[i] : eIdx) : bi1[i];
                    bv0[i] = l0 ? d : bv0[i];
                    bi0[i] = l0 ? eIdx : bi0[i];
                }
            }
        }
        __syncthreads();
    }

    float* out_q = out;
    float* out_i = out + (size_t)M * ZD;
    float* out_l = out_i + M;

    #pragma unroll 1
    for (int i = 0; i < 4; ++i) {
        const long r = rbase + g * 4 + i;
        const float* hrow = h + (size_t)r * ZD;

        float gmin = bv0[i];
        #pragma unroll
        for (int o = 1; o < 16; o <<= 1) gmin = fminf(gmin, __shfl_xor(gmin, o, 64));
        const float thr = gmin + taur[i];

        unsigned long long bal = __ballot(bv3[i] <= thr);
        const bool flagged = ((bal >> (g * 16)) & 0xFFFFull) != 0ull;

        float bestd = INF;
        int   besti = 0x7FFFFFFF;
        if (!flagged) {
            if (bv0[i] <= thr) {
                float dx = exact_d(hrow, emb + (size_t)bi0[i] * ZD, hnr[i], en[bi0[i]]);
                if (dx < bestd || (dx == bestd && bi0[i] < besti)) { bestd = dx; besti = bi0[i]; }
            }
            if (bv1[i] <= thr) {
                float dx = exact_d(hrow, emb + (size_t)bi1[i] * ZD, hnr[i], en[bi1[i]]);
                if (dx < bestd || (dx == bestd && bi1[i] < besti)) { bestd = dx; besti = bi1[i]; }
            }
            if (bv2[i] <= thr) {
                float dx = exact_d(hrow, emb + (size_t)bi2[i] * ZD, hnr[i], en[bi2[i]]);
                if (dx < bestd || (dx == bestd && bi2[i] < besti)) { bestd = dx; besti = bi2[i]; }
            }
            if (bv3[i] <= thr) {
                float dx = exact_d(hrow, emb + (size_t)bi3[i] * ZD, hnr[i], en[bi3[i]]);
                if (dx < bestd || (dx == bestd && bi3[i] < besti)) { bestd = dx; besti = bi3[i]; }
            }
        } else {
            // exhaustive fallback: two independent chains interleaved per lane
            // (entries e and e+16), float4 loads; evaluation order e < e2 keeps
            // the lowest-index tie-break identical to the serial version.
            for (int e = lg; e < NE; e += 32) {
                const int e2 = e + 16;
                const bool h2 = (e2 < NE);
                const float* er0 = emb + (size_t)e * ZD;
                const float* er1 = emb + (size_t)(h2 ? e2 : e) * ZD;
                float dot0 = 0.f, dot1 = 0.f;
                #pragma unroll 8
                for (int k = 0; k < ZD; k += 4) {
                    float4 hv = *(const float4*)(hrow + k);
                    float4 a = *(const float4*)(er0 + k);
                    float4 b = *(const float4*)(er1 + k);
                    dot0 = fmaf(hv.x, a.x, dot0); dot1 = fmaf(hv.x, b.x, dot1);
                    dot0 = fmaf(hv.y, a.y, dot0); dot1 = fmaf(hv.y, b.y, dot1);
                    dot0 = fmaf(hv.z, a.z, dot0); dot1 = fmaf(hv.z, b.z, dot1);
                    dot0 = fmaf(hv.w, a.w, dot0); dot1 = fmaf(hv.w, b.w, dot1);
                }
                float dx0 = __fsub_rn(__fadd_rn(hnr[i], en[e]), __fmul_rn(2.0f, dot0));
                if (dx0 < bestd || (dx0 == bestd && e < besti)) { bestd = dx0; besti = e; }
                if (h2) {
                    float dx1 = __fsub_rn(__fadd_rn(hnr[i], en[e2]), __fmul_rn(2.0f, dot1));
                    if (dx1 < bestd || (dx1 == bestd && e2 < besti)) { bestd = dx1; besti = e2; }
                }
            }
        }
        #pragma unroll
        for (int o = 1; o < 16; o <<= 1) {
            float ov = __shfl_xor(bestd, o, 64);
            int   oi = __shfl_xor(besti, o, 64);
            if (ov < bestd || (ov == bestd && oi < besti)) { bestd = ov; besti = oi; }
        }

        // epilogue (identical numerics to validated R1/R3 chain)
        const float* erow = emb + (size_t)besti * ZD;
        float csum = 0.0f;
        #pragma unroll
        for (int q4 = 0; q4 < 4; ++q4) {
            int k = lg * 16 + q4 * 4;
            float4 hv = *(const float4*)(hrow + k);
            float4 ev = *(const float4*)(erow + k);
            float dx = __fsub_rn(ev.x, hv.x);
            float dy = __fsub_rn(ev.y, hv.y);
            float dz = __fsub_rn(ev.z, hv.z);
            float dw = __fsub_rn(ev.w, hv.w);
            float4 o;
            o.x = __fadd_rn(hv.x, dx);
            o.y = __fadd_rn(hv.y, dy);
            o.z = __fadd_rn(hv.z, dz);
            o.w = __fadd_rn(hv.w, dw);
            *(float4*)(out_q + (size_t)r * ZD + k) = o;
            csum = fmaf(dx, dx, csum);
            csum = fmaf(dy, dy, csum);
            csum = fmaf(dz, dz, csum);
            csum = fmaf(dw, dw, csum);
        }
        #pragma unroll
        for (int o2 = 1; o2 < 16; o2 <<= 1) csum += __shfl_xor(csum, o2, 64);
        if (lg == 0) {
            float cmean = csum * (1.0f / 256.0f);
            out_i[r] = (float)besti;
            out_l[r] = __fadd_rn(__fmul_rn(cmean, 0.1f), __fmul_rn(cmean, 0.2f));
        }
    }
}

extern "C" void kernel_launch(void* const* d_in, const int* in_sizes, int n_in,
                              void* d_out, int out_size, void* d_ws, size_t ws_size,
                              hipStream_t stream) {
    const float* h   = (const float*)d_in[0];
    const float* emb = (const float*)d_in[1];
    const int M = in_sizes[0] / ZD;   // 131072

    unsigned char* ebB = (unsigned char*)d_ws;               // 512 KB bf16 swizzled
    float* en = (float*)(ebB + (size_t)NP * ZD * 2);         // 4 KB

    float* out = (float*)d_out;
    unsigned short* hb = (unsigned short*)d_out;             // bf16 h in out_q region
    float* hn = out + (size_t)M * ZD;                        // hn in out_i region

    prep_e<<<NP / 64, 64, 0, stream>>>(emb, ebB, en);
    prep_h<<<M / 64, 256, 0, stream>>>(h, hb, hn);

    const size_t lds_bytes = 131072 + 256 * sizeof(float);
    (void)hipFuncSetAttribute((const void*)vq_main,
                              hipFuncAttributeMaxDynamicSharedMemorySize,
                              (int)lds_bytes);
    vq_main<<<M / 256, 1024, lds_bytes, stream>>>(h, emb, ebB, en, out, M);
}